// Round 1
// baseline (2730.049 us; speedup 1.0000x reference)
//
#include <hip/hip_runtime.h>

// ---------------- types / helpers ----------------
typedef __attribute__((ext_vector_type(8))) short short8;
typedef __attribute__((ext_vector_type(4))) short short4v;
typedef __attribute__((ext_vector_type(4))) float float4v;
typedef __bf16 bf16x8 __attribute__((ext_vector_type(8)));

__device__ __forceinline__ float4v mfma16(short8 a, short8 b, float4v c) {
  return __builtin_amdgcn_mfma_f32_16x16x32_bf16(
      __builtin_bit_cast(bf16x8, a), __builtin_bit_cast(bf16x8, b), c, 0, 0, 0);
}

__device__ __forceinline__ short8 cat44(short4v a, short4v b) {
  short8 r;
  r[0]=a[0]; r[1]=a[1]; r[2]=a[2]; r[3]=a[3];
  r[4]=b[0]; r[5]=b[1]; r[6]=b[2]; r[7]=b[3];
  return r;
}

__device__ __forceinline__ unsigned short bf16_rne(float x) {
  unsigned u = __builtin_bit_cast(unsigned, x);
  u += 0x7fffu + ((u >> 16) & 1u);
  return (unsigned short)(u >> 16);
}
__device__ __forceinline__ float bf16_f(unsigned short h) {
  return __builtin_bit_cast(float, ((unsigned)h) << 16);
}
__device__ __forceinline__ void split_bf16(float x, unsigned short& hi, unsigned short& lo) {
  hi = bf16_rne(x);
  lo = bf16_rne(x - bf16_f(hi));
}

#define KLOG2E 1.442695041f
// sigmoid: 1/(1+e^-x)  tanh: 1-2/(e^{2x}+1)  (both safe at +-inf)
__device__ __forceinline__ float fast_sig(float x) {
  float z = __builtin_amdgcn_exp2f(-KLOG2E * x);
  return __builtin_amdgcn_rcpf(1.f + z);
}
__device__ __forceinline__ float fast_tanh(float x) {
  float z = __builtin_amdgcn_exp2f(2.f * KLOG2E * x);
  return 1.f - 2.f * __builtin_amdgcn_rcpf(1.f + z);
}

// sizes
// B=16 L=96 H=150 4H=600(pad 640) EMB=150(pad 160) 2H=300(pad 320)
// rows indexed row = t*16 + b  (t-major so one MFMA M-tile = all 16 batch at one t)

// ---------------- prep: weight fragment layouts + bf16 hi/lo splits ----------------
// fragment slot formula (same for A and B operands; consistency is what matters):
//   k(lane,e) = 32*kc + 16*(e>>2) + 4*(lane>>4) + (e&3)
__global__ void prep_kernel(
    const float* __restrict__ Wih0,   // [2][600][150]
    const float* __restrict__ WihR,   // [3][2][600][300]
    const float* __restrict__ Whh,    // [4][2][600][150]
    const float* __restrict__ bih,    // [4][2][600]
    const float* __restrict__ bhh,    // [4][2][600]
    const float* __restrict__ w1m,    // [100][600]
    const float* __restrict__ b1v,    // [100]
    unsigned short* __restrict__ whh_hi, unsigned short* __restrict__ whh_lo,
    unsigned short* __restrict__ wih_hi, unsigned short* __restrict__ wih_lo,
    unsigned short* __restrict__ wpr_hi, unsigned short* __restrict__ wpr_lo,
    float* __restrict__ bsum, float* __restrict__ b1cat)
{
  const int N_whh  = 8 * 40 * 5 * 512;   // 819200
  const int N_wih0 = 2 * 40 * 5 * 512;   // 204800
  const int N_wihr = 6 * 40 * 10 * 512;  // 1228800
  const int N_wpr  = 16 * 10 * 512;      // 81920
  const int N_bs   = 8 * 640;            // 5120
  const int total  = N_whh + N_wih0 + N_wihr + N_wpr + N_bs + 256;
  for (int i = blockIdx.x * blockDim.x + threadIdx.x; i < total;
       i += gridDim.x * blockDim.x) {
    int idx = i;
    if (idx < N_whh) {
      int e = idx & 7, lane = (idx >> 3) & 63, r = idx >> 9;
      int kc = r % 5; r /= 5; int nt = r % 40; int ld = r / 40;  // ld = layer*2+dir
      int g = 16 * nt + (lane & 15);
      int j = 32 * kc + 16 * (e >> 2) + 4 * (lane >> 4) + (e & 3);
      float v = (g < 600 && j < 150) ? Whh[((size_t)ld * 600 + g) * 150 + j] : 0.f;
      unsigned short h, l; split_bf16(v, h, l);
      whh_hi[idx] = h; whh_lo[idx] = l;
      continue;
    }
    idx -= N_whh;
    if (idx < N_wih0) {
      int e = idx & 7, lane = (idx >> 3) & 63, r = idx >> 9;
      int kc = r % 5; r /= 5; int nt = r % 40; int dir = r / 40;
      int g = 16 * nt + (lane & 15);
      int j = 32 * kc + 16 * (e >> 2) + 4 * (lane >> 4) + (e & 3);
      float v = (g < 600 && j < 150) ? Wih0[((size_t)dir * 600 + g) * 150 + j] : 0.f;
      unsigned short h, l; split_bf16(v, h, l);
      wih_hi[idx] = h; wih_lo[idx] = l;
      continue;
    }
    idx -= N_wih0;
    if (idx < N_wihr) {
      int e = idx & 7, lane = (idx >> 3) & 63, r = idx >> 9;
      int kc = r % 10; r /= 10; int nt = r % 40; int ld = r / 40;  // ld = (layer-1)*2+dir
      int g = 16 * nt + (lane & 15);
      int j = 32 * kc + 16 * (e >> 2) + 4 * (lane >> 4) + (e & 3);
      float v = (g < 600 && j < 300) ? WihR[((size_t)ld * 600 + g) * 300 + j] : 0.f;
      unsigned short h, l; split_bf16(v, h, l);
      wih_hi[N_wih0 + idx] = h; wih_lo[N_wih0 + idx] = l;
      continue;
    }
    idx -= N_wihr;
    if (idx < N_wpr) {
      int e = idx & 7, lane = (idx >> 3) & 63, r = idx >> 9;
      int kc = r % 10; int nt = r / 10;  // 16 tiles
      int ko = 16 * nt + (lane & 15);
      int j = 32 * kc + 16 * (e >> 2) + 4 * (lane >> 4) + (e & 3);
      float v = 0.f;
      if (j < 300) {
        if (ko < 100) v = w1m[(size_t)ko * 600 + j];             // head half
        else if (ko < 200) v = w1m[(size_t)(ko - 100) * 600 + 300 + j];  // dep half
      }
      unsigned short h, l; split_bf16(v, h, l);
      wpr_hi[idx] = h; wpr_lo[idx] = l;
      continue;
    }
    idx -= N_wpr;
    if (idx < N_bs) {
      int ld = idx / 640, g = idx - 640 * ld;
      bsum[idx] = (g < 600) ? bih[ld * 600 + g] + bhh[ld * 600 + g] : 0.f;
      continue;
    }
    idx -= N_bs;
    b1cat[idx] = (idx < 100) ? b1v[idx] : ((idx < 200) ? b1v[idx - 100] : 0.f);
  }
}

// ---------------- embedding gather -> xA (hi/lo), zero pads of xB ----------------
__global__ void embed_kernel(const int* __restrict__ widx, const int* __restrict__ pidx,
    const float* __restrict__ wemb, const float* __restrict__ temb,
    unsigned short* __restrict__ xa_hi, unsigned short* __restrict__ xa_lo,
    unsigned short* __restrict__ xb_hi, unsigned short* __restrict__ xb_lo)
{
  int row = blockIdx.x;       // t*16 + b
  int j = threadIdx.x;        // 0..319
  int b = row & 15, t = row >> 4;
  float v = 0.f;
  if (j < 100) v = wemb[(size_t)widx[b * 96 + t] * 100 + j];
  else if (j < 150) v = temb[(size_t)pidx[b * 96 + t] * 50 + (j - 100)];
  unsigned short h, l; split_bf16(v, h, l);
  size_t o = (size_t)row * 320 + j;
  xa_hi[o] = h; xa_lo[o] = l;
  if (j >= 300) { xb_hi[o] = 0; xb_lo[o] = 0; }
}

// ---------------- pre-GEMM: pre[d][t][b][g] = x @ Wih^T + b_ih + b_hh ----------------
template <int KC>
__global__ __launch_bounds__(512) void pregemm_kernel(
    const unsigned short* __restrict__ x_hi, const unsigned short* __restrict__ x_lo,
    const unsigned short* __restrict__ wih_h, const unsigned short* __restrict__ wih_l,
    const float* __restrict__ bsum_l,   // [2][640] this layer
    float* __restrict__ pre)            // [2][96][16][640]
{
  const int t = blockIdx.x, dir = blockIdx.y;
  const int tid = threadIdx.x, wv = tid >> 6, lane = tid & 63;
  const int lrow = lane & 15, lgrp = lane >> 4;
  const unsigned short* wh = wih_h + (size_t)dir * 40 * KC * 512;
  const unsigned short* wl = wih_l + (size_t)dir * 40 * KC * 512;
  float4v acc[5];
#pragma unroll
  for (int tt = 0; tt < 5; ++tt) acc[tt] = (float4v){0.f, 0.f, 0.f, 0.f};
  const size_t arow = ((size_t)t * 16 + lrow) * 320;
#pragma unroll
  for (int kc = 0; kc < KC; ++kc) {
    int co = 32 * kc + 4 * lgrp;
    short8 ah = cat44(*(const short4v*)(x_hi + arow + co),
                      *(const short4v*)(x_hi + arow + co + 16));
    short8 al = cat44(*(const short4v*)(x_lo + arow + co),
                      *(const short4v*)(x_lo + arow + co + 16));
#pragma unroll
    for (int tt = 0; tt < 5; ++tt) {
      int nt = 5 * wv + tt;
      const size_t wo = ((size_t)(nt * KC + kc) * 64 + lane) * 8;
      short8 bh = *(const short8*)(wh + wo);
      short8 bl = *(const short8*)(wl + wo);
      acc[tt] = mfma16(ah, bh, acc[tt]);
      acc[tt] = mfma16(al, bh, acc[tt]);
      acc[tt] = mfma16(ah, bl, acc[tt]);
    }
  }
  float* po = pre + ((size_t)dir * 96 + t) * 16 * 640;
  const float* bs = bsum_l + dir * 640;
#pragma unroll
  for (int tt = 0; tt < 5; ++tt) {
    int g = 16 * (5 * wv + tt) + lrow;
    float bv = bs[g];
#pragma unroll
    for (int jj = 0; jj < 4; ++jj)
      po[(size_t)(4 * lgrp + jj) * 640 + g] = acc[tt][jj] + bv;
  }
}

// ---------------- sequential LSTM scan, one block per direction ----------------
__global__ __launch_bounds__(512) void scan_kernel(
    const float* __restrict__ pre,                 // [2][96][16][640]
    const unsigned short* __restrict__ whh_hi,
    const unsigned short* __restrict__ whh_lo,
    unsigned short* __restrict__ xo_hi, unsigned short* __restrict__ xo_lo, // [1536][320]
    int layer)
{
  const int dir = blockIdx.x;
  const int tid = threadIdx.x, wv = tid >> 6, lane = tid & 63;
  const int lrow = lane & 15, lgrp = lane >> 4;

  // h in MFMA A-fragment order: pos = b*168 + kc*32 + q*8 + e   (q = lane>>4)
  __shared__ __align__(16) unsigned short h_hi[16 * 168];
  __shared__ __align__(16) unsigned short h_lo[16 * 168];
  __shared__ float gates[16 * 644];

  for (int i = tid; i < 16 * 168; i += 512) { h_hi[i] = 0; h_lo[i] = 0; }

  // Whh fragments resident in VGPRs (invariant over timesteps)
  const unsigned short* bh_base = whh_hi + (size_t)(layer * 2 + dir) * 40 * 5 * 512;
  const unsigned short* bl_base = whh_lo + (size_t)(layer * 2 + dir) * 40 * 5 * 512;
  short8 Bh[5][5], Bl[5][5];
#pragma unroll
  for (int tt = 0; tt < 5; ++tt)
#pragma unroll
    for (int kc = 0; kc < 5; ++kc) {
      size_t o = ((size_t)((5 * wv + tt) * 5 + kc) * 64 + lane) * 8;
      Bh[tt][kc] = *(const short8*)(bh_base + o);
      Bl[tt][kc] = *(const short8*)(bl_base + o);
    }

  float cst[5];
#pragma unroll
  for (int ii = 0; ii < 5; ++ii) cst[ii] = 0.f;

  const float* preD = pre + (size_t)dir * 96 * 16 * 640;
  __syncthreads();

#pragma unroll 1
  for (int step = 0; step < 96; ++step) {
    const int t = dir ? (95 - step) : step;
    const float* pt = preD + (size_t)t * 16 * 640;

    // prefetch pre-activations (consumed after MFMA phase)
    float prv[5][4];
#pragma unroll
    for (int tt = 0; tt < 5; ++tt) {
      int g = 16 * (5 * wv + tt) + lrow;
#pragma unroll
      for (int jj = 0; jj < 4; ++jj)
        prv[tt][jj] = pt[(size_t)(4 * lgrp + jj) * 640 + g];
    }

    float4v acc[5];
#pragma unroll
    for (int tt = 0; tt < 5; ++tt) acc[tt] = (float4v){0.f, 0.f, 0.f, 0.f};

#pragma unroll
    for (int kc = 0; kc < 5; ++kc) {
      const int ao = lrow * 168 + kc * 32 + lgrp * 8;
      short8 ah = *(const short8*)(h_hi + ao);
      short8 al = *(const short8*)(h_lo + ao);
#pragma unroll
      for (int tt = 0; tt < 5; ++tt) {
        acc[tt] = mfma16(ah, Bh[tt][kc], acc[tt]);
        acc[tt] = mfma16(al, Bh[tt][kc], acc[tt]);
        acc[tt] = mfma16(ah, Bl[tt][kc], acc[tt]);
      }
    }

    // gate nonlinearity on the VALU (overlaps the MFMA pipe), write to LDS
#pragma unroll
    for (int tt = 0; tt < 5; ++tt) {
      const int g = 16 * (5 * wv + tt) + lrow;
      const bool isT = (g >= 300) && (g < 450);      // g-gate -> tanh, others sigmoid
      const float kf = isT ? (2.f * KLOG2E) : (-KLOG2E);
      const float af = isT ? 1.f : 0.f;
      const float bf = isT ? 2.f : -1.f;
#pragma unroll
      for (int jj = 0; jj < 4; ++jj) {
        float x = acc[tt][jj] + prv[tt][jj];
        float z = __builtin_amdgcn_exp2f(kf * x);
        float y = af - bf * __builtin_amdgcn_rcpf(1.f + z);
        gates[(4 * lgrp + jj) * 644 + g] = y;
      }
    }
    __syncthreads();

    // state update: thread owns fixed (b,j) cells, c kept in registers
#pragma unroll
    for (int ii = 0; ii < 5; ++ii) {
      int e = tid + 512 * ii;
      if (e < 2400) {
        int b = e / 150;
        int j = e - 150 * b;
        float gi = gates[b * 644 + j];
        float gf = gates[b * 644 + 150 + j];
        float gg = gates[b * 644 + 300 + j];
        float go = gates[b * 644 + 450 + j];
        float c = gf * cst[ii] + gi * gg;
        cst[ii] = c;
        float h = go * fast_tanh(c);
        unsigned short hh, hl; split_bf16(h, hh, hl);
        int kc = j >> 5, w = j & 31;
        int off = b * 168 + kc * 32 + ((w >> 2) & 3) * 8 + (w >> 4) * 4 + (w & 3);
        h_hi[off] = hh; h_lo[off] = hl;
        size_t gout = ((size_t)t * 16 + b) * 320 + dir * 150 + j;
        xo_hi[gout] = hh; xo_lo[gout] = hl;
      }
    }
    __syncthreads();
  }
}

// ---------------- elementwise degree-4 polynomial ----------------
__global__ void poly_kernel(const unsigned short* __restrict__ xi_hi,
    const unsigned short* __restrict__ xi_lo,
    unsigned short* __restrict__ xo_hi, unsigned short* __restrict__ xo_lo,
    const float* __restrict__ w1, const float* __restrict__ w2,
    const float* __restrict__ w3, const float* __restrict__ w4)
{
  int i = blockIdx.x * 256 + threadIdx.x;
  if (i >= 1536 * 320) return;
  float x = bf16_f(xi_hi[i]) + bf16_f(xi_lo[i]);
  float p = x * (w1[0] + x * (w2[0] + x * (w3[0] + x * w4[0])));
  unsigned short h, l; split_bf16(p, h, l);
  xo_hi[i] = h; xo_lo[i] = l;
}

// ---------------- projection: AD[row][0:100]=A'(+b1), [100:200]=D ----------------
__global__ __launch_bounds__(512) void proj_kernel(
    const unsigned short* __restrict__ p_hi, const unsigned short* __restrict__ p_lo,
    const unsigned short* __restrict__ wpr_hi, const unsigned short* __restrict__ wpr_lo,
    const float* __restrict__ b1cat,
    float* __restrict__ AD)   // [1536][256]
{
  const int t = blockIdx.x;
  const int tid = threadIdx.x, wv = tid >> 6, lane = tid & 63;
  const int lrow = lane & 15, lgrp = lane >> 4;
  float4v acc[2] = {{0.f, 0.f, 0.f, 0.f}, {0.f, 0.f, 0.f, 0.f}};
  const size_t arow = ((size_t)t * 16 + lrow) * 320;
#pragma unroll
  for (int kc = 0; kc < 10; ++kc) {
    int co = 32 * kc + 4 * lgrp;
    short8 ah = cat44(*(const short4v*)(p_hi + arow + co),
                      *(const short4v*)(p_hi + arow + co + 16));
    short8 al = cat44(*(const short4v*)(p_lo + arow + co),
                      *(const short4v*)(p_lo + arow + co + 16));
#pragma unroll
    for (int tt = 0; tt < 2; ++tt) {
      int nt = 2 * wv + tt;
      size_t wo = ((size_t)(nt * 10 + kc) * 64 + lane) * 8;
      short8 bh = *(const short8*)(wpr_hi + wo);
      short8 bl = *(const short8*)(wpr_lo + wo);
      acc[tt] = mfma16(ah, bh, acc[tt]);
      acc[tt] = mfma16(al, bh, acc[tt]);
      acc[tt] = mfma16(ah, bl, acc[tt]);
    }
  }
#pragma unroll
  for (int tt = 0; tt < 2; ++tt) {
    int ko = 16 * (2 * wv + tt) + lrow;
    float bv = b1cat[ko];
#pragma unroll
    for (int jj = 0; jj < 4; ++jj)
      AD[((size_t)t * 16 + 4 * lgrp + jj) * 256 + ko] = acc[tt][jj] + bv;
  }
}

// ---------------- combine: out[lh][b][ld] = b2 + sum_k w2[k]*tanh(A+D) ----------------
__global__ __launch_bounds__(768) void combine_kernel(
    const float* __restrict__ AD, const float* __restrict__ w2v,
    const float* __restrict__ b2v, float* __restrict__ out)
{
  const int bb = blockIdx.x & 15, lt = blockIdx.x >> 4;
  const int tid = threadIdx.x;
  __shared__ float Dl[100 * 97];  // [k][ld], stride 97
  __shared__ float Al[100 * 9];   // [k][lh], stride 9
  __shared__ float w2s[100];
  for (int i = tid; i < 96 * 32; i += 768) {
    int ld = i >> 5, f4 = i & 31;
    if (f4 < 25) {
      float4v v = *(const float4v*)(AD + ((size_t)ld * 16 + bb) * 256 + 100 + 4 * f4);
      int k0 = 4 * f4;
      Dl[(k0 + 0) * 97 + ld] = v[0];
      Dl[(k0 + 1) * 97 + ld] = v[1];
      Dl[(k0 + 2) * 97 + ld] = v[2];
      Dl[(k0 + 3) * 97 + ld] = v[3];
    }
  }
  for (int i = tid; i < 8 * 32; i += 768) {
    int lh = i >> 5, f4 = i & 31;
    if (f4 < 25) {
      int lseq = lt * 8 + lh;
      float4v v = *(const float4v*)(AD + ((size_t)lseq * 16 + bb) * 256 + 4 * f4);
      int k0 = 4 * f4;
      Al[(k0 + 0) * 9 + lh] = v[0];
      Al[(k0 + 1) * 9 + lh] = v[1];
      Al[(k0 + 2) * 9 + lh] = v[2];
      Al[(k0 + 3) * 9 + lh] = v[3];
    }
  }
  if (tid < 100) w2s[tid] = w2v[tid];
  __syncthreads();
  int lh = tid / 96, ld = tid - 96 * lh;
  float s = 0.f;
#pragma unroll 4
  for (int k = 0; k < 100; ++k) {
    float x = Al[k * 9 + lh] + Dl[k * 97 + ld];
    s += w2s[k] * fast_tanh(x);
  }
  out[((size_t)(lt * 8 + lh) * 16 + bb) * 96 + ld] = s + b2v[0];
}

// ---------------- host ----------------
extern "C" void kernel_launch(void* const* d_in, const int* in_sizes, int n_in,
                              void* d_out, int out_size, void* d_ws, size_t ws_size,
                              hipStream_t stream)
{
  const int*   widx = (const int*)d_in[0];
  const int*   pidx = (const int*)d_in[1];
  const float* wemb = (const float*)d_in[3];
  const float* temb = (const float*)d_in[4];
  const float* Wih0 = (const float*)d_in[5];
  const float* WihR = (const float*)d_in[6];
  const float* Whh  = (const float*)d_in[7];
  const float* bih  = (const float*)d_in[8];
  const float* bhh  = (const float*)d_in[9];
  const float* w1   = (const float*)d_in[10];
  const float* w2   = (const float*)d_in[11];
  const float* w3   = (const float*)d_in[12];
  const float* w4   = (const float*)d_in[13];
  const float* w1m  = (const float*)d_in[14];
  const float* b1v  = (const float*)d_in[15];
  const float* w2m  = (const float*)d_in[16];
  const float* b2v  = (const float*)d_in[17];
  float* out = (float*)d_out;

  char* ws = (char*)d_ws;
  size_t off = 0;
  auto alloc = [&](size_t bytes) -> char* {
    char* p = ws + off;
    off = (off + bytes + 255) & ~(size_t)255;
    return p;
  };
  unsigned short* WHH_HI = (unsigned short*)alloc(819200ull * 2);
  unsigned short* WHH_LO = (unsigned short*)alloc(819200ull * 2);
  unsigned short* WIH_HI = (unsigned short*)alloc(1433600ull * 2);
  unsigned short* WIH_LO = (unsigned short*)alloc(1433600ull * 2);
  unsigned short* WPR_HI = (unsigned short*)alloc(81920ull * 2);
  unsigned short* WPR_LO = (unsigned short*)alloc(81920ull * 2);
  float* BSUM = (float*)alloc(5120ull * 4);
  float* B1C  = (float*)alloc(256ull * 4);
  unsigned short* XA_HI = (unsigned short*)alloc(491520ull * 2);
  unsigned short* XA_LO = (unsigned short*)alloc(491520ull * 2);
  unsigned short* XB_HI = (unsigned short*)alloc(491520ull * 2);
  unsigned short* XB_LO = (unsigned short*)alloc(491520ull * 2);
  float* PRE = (float*)alloc(1966080ull * 4);
  float* AD  = (float*)alloc(1536ull * 256 * 4);

  prep_kernel<<<512, 256, 0, stream>>>(Wih0, WihR, Whh, bih, bhh, w1m, b1v,
      WHH_HI, WHH_LO, WIH_HI, WIH_LO, WPR_HI, WPR_LO, BSUM, B1C);
  embed_kernel<<<1536, 320, 0, stream>>>(widx, pidx, wemb, temb,
      XA_HI, XA_LO, XB_HI, XB_LO);

  for (int layer = 0; layer < 4; ++layer) {
    const unsigned short* xin_hi = (layer & 1) ? XB_HI : XA_HI;
    const unsigned short* xin_lo = (layer & 1) ? XB_LO : XA_LO;
    unsigned short* xo_hi = (layer & 1) ? XA_HI : XB_HI;
    unsigned short* xo_lo = (layer & 1) ? XA_LO : XB_LO;
    const float* bsl = BSUM + layer * 2 * 640;
    if (layer == 0) {
      pregemm_kernel<5><<<dim3(96, 2), 512, 0, stream>>>(
          xin_hi, xin_lo, WIH_HI, WIH_LO, bsl, PRE);
    } else {
      size_t wo = 204800ull + (size_t)(layer - 1) * 409600ull;
      pregemm_kernel<10><<<dim3(96, 2), 512, 0, stream>>>(
          xin_hi, xin_lo, WIH_HI + wo, WIH_LO + wo, bsl, PRE);
    }
    scan_kernel<<<2, 512, 0, stream>>>(PRE, WHH_HI, WHH_LO, xo_hi, xo_lo, layer);
  }
  // layer-3 output sits in XA; poly -> XB; proj -> AD; combine -> out
  poly_kernel<<<1920, 256, 0, stream>>>(XA_HI, XA_LO, XB_HI, XB_LO, w1, w2, w3, w4);
  proj_kernel<<<96, 512, 0, stream>>>(XB_HI, XB_LO, WPR_HI, WPR_LO, B1C, AD);
  combine_kernel<<<192, 768, 0, stream>>>(AD, w2m, b2v, out);
}